// Round 6
// baseline (318.798 us; speedup 1.0000x reference)
//
#include <hip/hip_runtime.h>
#include <math.h>

// CasperNet R6: B=131072, D=256, H=64, O=10.
// vs R5 (180us, occ 22.8%, VALUBusy 41%): latency-bound cascade chain.
//  - BLOCK=512 (8 waves), TM=256: same LDS/block -> still 2 blocks/CU but
//    16 waves/CU (50% occ, was 22.8%).
//  - 2 row-tiles per wave (u=0,1): two independent cascade chains per wave
//    interleave (ILP); B-frags + cascade weights reused across tiles.
//  - sigmoid via v_rcp_f32 (__builtin_amdgcn_rcpf) instead of IEEE divide
//    (~10 serial instr off the per-step dependency chain).
// Layout (verified R5): MFMA C: col=lane&15, row=(lane>>4)*4+reg.

#define DIMD 256
#define DIMH 64
#define DIMO 10
#define DT   320
#define NT   5        // 5 n-tiles of 16 = 80 cols (74 used)
#define TM   256      // rows per block: 8 waves x 32
#define BLOCK 512

typedef __attribute__((ext_vector_type(4))) float f32x4;
typedef __attribute__((ext_vector_type(8))) short bf16x8;

__device__ inline unsigned short f2bf(float f) {
    union { float f; unsigned u; } v; v.f = f;
    unsigned r = v.u + 0x7FFFu + ((v.u >> 16) & 1u);   // RNE
    return (unsigned short)(r >> 16);
}

__device__ inline float sigm(float s) {
    return __builtin_amdgcn_rcpf(1.0f + __expf(-s));   // v_rcp_f32: 1 instr
}

__global__ __launch_bounds__(BLOCK, 4) void caspernet_kernel(
    const float* __restrict__ x,    // [B, 256]
    const float* __restrict__ Wh,   // [64, 320]
    const float* __restrict__ bh,   // [64]
    const float* __restrict__ Wo,   // [10, 320]
    const float* __restrict__ bo,   // [10]
    float* __restrict__ out,        // [B, 10]
    int B)
{
    __shared__ short sW[80 * DIMD];     // bf16 [n][k], k XOR-swizzled; 40KB
    __shared__ f32x4 sU4[DIMH * 16];    // [i][c]: U for cols c+16t;     16KB
    __shared__ float sWoh[DIMH * 16];   // [i][c]: head col c (0 pad);    4KB
    __shared__ float sBias[80];

    const int tid = threadIdx.x;

    // ---- stage W1 = [Wh_x; Wo_x] as bf16, swizzled ----
    for (int idx = tid; idx < 80 * 64; idx += BLOCK) {   // 80 rows x 64 float4
        const int n = idx >> 6, k0 = (idx & 63) * 4;
        float4 v = make_float4(0.f, 0.f, 0.f, 0.f);
        if (n < DIMH)      v = *reinterpret_cast<const float4*>(Wh + n * DT + k0);
        else if (n < 74)   v = *reinterpret_cast<const float4*>(Wo + (n - 64) * DT + k0);
        const int kz = k0 ^ ((n & 7) << 3);
        short* d = sW + n * DIMD + kz;
        d[0] = (short)f2bf(v.x); d[1] = (short)f2bf(v.y);
        d[2] = (short)f2bf(v.z); d[3] = (short)f2bf(v.w);
    }
    // ---- cascade weights (pre-masked) + head + bias ----
    for (int idx = tid; idx < DIMH * 16; idx += BLOCK) {
        const int i = idx >> 4, c = idx & 15;
        f32x4 u;
        u[0] = (c      > i) ? Wh[(c     ) * DT + DIMD + i] : 0.f;
        u[1] = (16 + c > i) ? Wh[(16 + c) * DT + DIMD + i] : 0.f;
        u[2] = (32 + c > i) ? Wh[(32 + c) * DT + DIMD + i] : 0.f;
        u[3] = (48 + c > i) ? Wh[(48 + c) * DT + DIMD + i] : 0.f;
        sU4[idx] = u;
        sWoh[idx] = (c < DIMO) ? Wo[c * DT + DIMD + i] : 0.f;
    }
    if (tid < 80) sBias[tid] = (tid < 64) ? bh[tid] : ((tid < 74) ? bo[tid - 64] : 0.f);
    __syncthreads();

    const int l  = tid & 63;
    const int w  = tid >> 6;            // wave 0..7 -> rows w*32 .. w*32+31
    const int lm = l & 15, lg = l >> 4;
    const size_t rowbase = (size_t)blockIdx.x * TM + w * 32;

    // ---- phase 1: two 16-row tiles per wave ----
    const float* xr0 = x + (rowbase +      lm) * DIMD + lg * 8;
    const float* xr1 = x + (rowbase + 16 + lm) * DIMD + lg * 8;

    f32x4 acc[2][NT];
    #pragma unroll
    for (int u = 0; u < 2; ++u)
        #pragma unroll
        for (int t = 0; t < NT; ++t) acc[u][t] = (f32x4){0.f, 0.f, 0.f, 0.f};

    #pragma unroll
    for (int ks = 0; ks < 8; ++ks) {
        const float4 xa0 = *reinterpret_cast<const float4*>(xr0 + ks * 32);
        const float4 xb0 = *reinterpret_cast<const float4*>(xr0 + ks * 32 + 4);
        const float4 xa1 = *reinterpret_cast<const float4*>(xr1 + ks * 32);
        const float4 xb1 = *reinterpret_cast<const float4*>(xr1 + ks * 32 + 4);
        bf16x8 af0, af1;
        af0[0] = (short)f2bf(xa0.x); af0[1] = (short)f2bf(xa0.y);
        af0[2] = (short)f2bf(xa0.z); af0[3] = (short)f2bf(xa0.w);
        af0[4] = (short)f2bf(xb0.x); af0[5] = (short)f2bf(xb0.y);
        af0[6] = (short)f2bf(xb0.z); af0[7] = (short)f2bf(xb0.w);
        af1[0] = (short)f2bf(xa1.x); af1[1] = (short)f2bf(xa1.y);
        af1[2] = (short)f2bf(xa1.z); af1[3] = (short)f2bf(xa1.w);
        af1[4] = (short)f2bf(xb1.x); af1[5] = (short)f2bf(xb1.y);
        af1[6] = (short)f2bf(xb1.z); af1[7] = (short)f2bf(xb1.w);
        #pragma unroll
        for (int t = 0; t < NT; ++t) {
            const int n = t * 16 + lm;
            const int kz = (lg * 8 + ks * 32) ^ ((n & 7) << 3);
            const bf16x8 bf = *reinterpret_cast<const bf16x8*>(sW + n * DIMD + kz);
            acc[0][t] = __builtin_amdgcn_mfma_f32_16x16x32_bf16(af0, bf, acc[0][t], 0, 0, 0);
            acc[1][t] = __builtin_amdgcn_mfma_f32_16x16x32_bf16(af1, bf, acc[1][t], 0, 0, 0);
        }
    }
    #pragma unroll
    for (int t = 0; t < NT; ++t) {
        const float bt = sBias[t * 16 + lm];
        #pragma unroll
        for (int u = 0; u < 2; ++u) {
            acc[u][t][0] += bt; acc[u][t][1] += bt;
            acc[u][t][2] += bt; acc[u][t][3] += bt;
        }
    }

    // ---- phase 2: two interleaved cascade chains ----
    const int gbase = l & 48;
    #pragma unroll
    for (int i = 0; i < DIMH; ++i) {
        const int ti = i >> 4, ci = i & 15;
        float h[2][4];
        #pragma unroll
        for (int u = 0; u < 2; ++u) {
            const float s0 = __shfl(acc[u][ti][0], gbase | ci, 64);
            const float s1 = __shfl(acc[u][ti][1], gbase | ci, 64);
            const float s2 = __shfl(acc[u][ti][2], gbase | ci, 64);
            const float s3 = __shfl(acc[u][ti][3], gbase | ci, 64);
            h[u][0] = sigm(s0); h[u][1] = sigm(s1);
            h[u][2] = sigm(s2); h[u][3] = sigm(s3);
        }
        const f32x4 uv = sU4[i * 16 + lm];
        const float wo = sWoh[i * 16 + lm];
        #pragma unroll
        for (int u = 0; u < 2; ++u) {
            #pragma unroll
            for (int t = ti; t < 4; ++t) {     // cols <= i carry zero weights
                acc[u][t][0] = fmaf(uv[t], h[u][0], acc[u][t][0]);
                acc[u][t][1] = fmaf(uv[t], h[u][1], acc[u][t][1]);
                acc[u][t][2] = fmaf(uv[t], h[u][2], acc[u][t][2]);
                acc[u][t][3] = fmaf(uv[t], h[u][3], acc[u][t][3]);
            }
            acc[u][4][0] = fmaf(wo, h[u][0], acc[u][4][0]);
            acc[u][4][1] = fmaf(wo, h[u][1], acc[u][4][1]);
            acc[u][4][2] = fmaf(wo, h[u][2], acc[u][4][2]);
            acc[u][4][3] = fmaf(wo, h[u][3], acc[u][4][3]);
        }
    }

    // ---- store head tile (cols 64..73) for both row-tiles ----
    if (lm < DIMO) {
        #pragma unroll
        for (int u = 0; u < 2; ++u) {
            const size_t orow0 = rowbase + u * 16 + lg * 4;
            #pragma unroll
            for (int r = 0; r < 4; ++r)
                out[(orow0 + r) * DIMO + lm] = acc[u][4][r];
        }
    }
}

extern "C" void kernel_launch(void* const* d_in, const int* in_sizes, int n_in,
                              void* d_out, int out_size, void* d_ws, size_t ws_size,
                              hipStream_t stream) {
    const float* x  = (const float*)d_in[0];
    const float* Wh = (const float*)d_in[1];
    const float* bh = (const float*)d_in[2];
    const float* Wo = (const float*)d_in[3];
    const float* bo = (const float*)d_in[4];
    float* out = (float*)d_out;

    const int B = in_sizes[0] / DIMD;      // 131072
    const int grid = B / TM;               // 512

    hipLaunchKernelGGL(caspernet_kernel, dim3(grid), dim3(BLOCK), 0, stream,
                       x, Wh, bh, Wo, bo, out, B);
}

// Round 7
// 264.057 us; speedup vs baseline: 1.2073x; 1.2073x over previous
//
#include <hip/hip_runtime.h>
#include <math.h>

// CasperNet R7: B=131072, D=256, H=64, O=10.
// R6 (318us) spilled again: empirically hipcc treats __launch_bounds__'s
// 2nd arg like CUDA min-BLOCKS-per-CU (R3 (1024,4)->64 VGPR, R5 (256,4)->88,
// R6 (512,4)->64). Fix: (512,2) -> 16 waves/CU -> 128-VGPR cap under the
// blocks reading (256 under the waves/EU reading) -- no spill either way.
// LDS 61KB independently caps at 2 blocks/CU = 16 waves = 50% occupancy.
// Structure unchanged vs R6: MFMA phase-1 (C-layout col=lane&15,
// row=(lane>>4)*4+reg), cascade directly on C-frags, 2 independent
// row-tile chains per wave for ILP, sigmoid via v_rcp_f32.

#define DIMD 256
#define DIMH 64
#define DIMO 10
#define DT   320
#define NT   5        // 5 n-tiles of 16 = 80 cols (74 used)
#define TM   256      // rows per block: 8 waves x 32
#define BLOCK 512

typedef __attribute__((ext_vector_type(4))) float f32x4;
typedef __attribute__((ext_vector_type(8))) short bf16x8;

__device__ inline unsigned short f2bf(float f) {
    union { float f; unsigned u; } v; v.f = f;
    unsigned r = v.u + 0x7FFFu + ((v.u >> 16) & 1u);   // RNE
    return (unsigned short)(r >> 16);
}

__device__ inline float sigm(float s) {
    return __builtin_amdgcn_rcpf(1.0f + __expf(-s));   // v_rcp_f32: 1 instr
}

__global__ __launch_bounds__(BLOCK, 2) void caspernet_kernel(
    const float* __restrict__ x,    // [B, 256]
    const float* __restrict__ Wh,   // [64, 320]
    const float* __restrict__ bh,   // [64]
    const float* __restrict__ Wo,   // [10, 320]
    const float* __restrict__ bo,   // [10]
    float* __restrict__ out,        // [B, 10]
    int B)
{
    __shared__ short sW[80 * DIMD];     // bf16 [n][k], k XOR-swizzled; 40KB
    __shared__ f32x4 sU4[DIMH * 16];    // [i][c]: U for cols c+16t;     16KB
    __shared__ float sWoh[DIMH * 16];   // [i][c]: head col c (0 pad);    4KB
    __shared__ float sBias[80];

    const int tid = threadIdx.x;

    // ---- stage W1 = [Wh_x; Wo_x] as bf16, swizzled ----
    for (int idx = tid; idx < 80 * 64; idx += BLOCK) {   // 80 rows x 64 float4
        const int n = idx >> 6, k0 = (idx & 63) * 4;
        float4 v = make_float4(0.f, 0.f, 0.f, 0.f);
        if (n < DIMH)      v = *reinterpret_cast<const float4*>(Wh + n * DT + k0);
        else if (n < 74)   v = *reinterpret_cast<const float4*>(Wo + (n - 64) * DT + k0);
        const int kz = k0 ^ ((n & 7) << 3);
        short* d = sW + n * DIMD + kz;
        d[0] = (short)f2bf(v.x); d[1] = (short)f2bf(v.y);
        d[2] = (short)f2bf(v.z); d[3] = (short)f2bf(v.w);
    }
    // ---- cascade weights (pre-masked) + head + bias ----
    for (int idx = tid; idx < DIMH * 16; idx += BLOCK) {
        const int i = idx >> 4, c = idx & 15;
        f32x4 u;
        u[0] = (c      > i) ? Wh[(c     ) * DT + DIMD + i] : 0.f;
        u[1] = (16 + c > i) ? Wh[(16 + c) * DT + DIMD + i] : 0.f;
        u[2] = (32 + c > i) ? Wh[(32 + c) * DT + DIMD + i] : 0.f;
        u[3] = (48 + c > i) ? Wh[(48 + c) * DT + DIMD + i] : 0.f;
        sU4[idx] = u;
        sWoh[idx] = (c < DIMO) ? Wo[c * DT + DIMD + i] : 0.f;
    }
    if (tid < 80) sBias[tid] = (tid < 64) ? bh[tid] : ((tid < 74) ? bo[tid - 64] : 0.f);
    __syncthreads();

    const int l  = tid & 63;
    const int w  = tid >> 6;            // wave 0..7 -> rows w*32 .. w*32+31
    const int lm = l & 15, lg = l >> 4;
    const size_t rowbase = (size_t)blockIdx.x * TM + w * 32;

    // ---- phase 1: two 16-row tiles per wave ----
    const float* xr0 = x + (rowbase +      lm) * DIMD + lg * 8;
    const float* xr1 = x + (rowbase + 16 + lm) * DIMD + lg * 8;

    f32x4 acc[2][NT];
    #pragma unroll
    for (int u = 0; u < 2; ++u)
        #pragma unroll
        for (int t = 0; t < NT; ++t) acc[u][t] = (f32x4){0.f, 0.f, 0.f, 0.f};

    #pragma unroll
    for (int ks = 0; ks < 8; ++ks) {
        const float4 xa0 = *reinterpret_cast<const float4*>(xr0 + ks * 32);
        const float4 xb0 = *reinterpret_cast<const float4*>(xr0 + ks * 32 + 4);
        const float4 xa1 = *reinterpret_cast<const float4*>(xr1 + ks * 32);
        const float4 xb1 = *reinterpret_cast<const float4*>(xr1 + ks * 32 + 4);
        bf16x8 af0, af1;
        af0[0] = (short)f2bf(xa0.x); af0[1] = (short)f2bf(xa0.y);
        af0[2] = (short)f2bf(xa0.z); af0[3] = (short)f2bf(xa0.w);
        af0[4] = (short)f2bf(xb0.x); af0[5] = (short)f2bf(xb0.y);
        af0[6] = (short)f2bf(xb0.z); af0[7] = (short)f2bf(xb0.w);
        af1[0] = (short)f2bf(xa1.x); af1[1] = (short)f2bf(xa1.y);
        af1[2] = (short)f2bf(xa1.z); af1[3] = (short)f2bf(xa1.w);
        af1[4] = (short)f2bf(xb1.x); af1[5] = (short)f2bf(xb1.y);
        af1[6] = (short)f2bf(xb1.z); af1[7] = (short)f2bf(xb1.w);
        #pragma unroll
        for (int t = 0; t < NT; ++t) {
            const int n = t * 16 + lm;
            const int kz = (lg * 8 + ks * 32) ^ ((n & 7) << 3);
            const bf16x8 bf = *reinterpret_cast<const bf16x8*>(sW + n * DIMD + kz);
            acc[0][t] = __builtin_amdgcn_mfma_f32_16x16x32_bf16(af0, bf, acc[0][t], 0, 0, 0);
            acc[1][t] = __builtin_amdgcn_mfma_f32_16x16x32_bf16(af1, bf, acc[1][t], 0, 0, 0);
        }
    }
    #pragma unroll
    for (int t = 0; t < NT; ++t) {
        const float bt = sBias[t * 16 + lm];
        #pragma unroll
        for (int u = 0; u < 2; ++u) {
            acc[u][t][0] += bt; acc[u][t][1] += bt;
            acc[u][t][2] += bt; acc[u][t][3] += bt;
        }
    }

    // ---- phase 2: two interleaved cascade chains ----
    const int gbase = l & 48;
    #pragma unroll
    for (int i = 0; i < DIMH; ++i) {
        const int ti = i >> 4, ci = i & 15;
        float h[2][4];
        #pragma unroll
        for (int u = 0; u < 2; ++u) {
            const float s0 = __shfl(acc[u][ti][0], gbase | ci, 64);
            const float s1 = __shfl(acc[u][ti][1], gbase | ci, 64);
            const float s2 = __shfl(acc[u][ti][2], gbase | ci, 64);
            const float s3 = __shfl(acc[u][ti][3], gbase | ci, 64);
            h[u][0] = sigm(s0); h[u][1] = sigm(s1);
            h[u][2] = sigm(s2); h[u][3] = sigm(s3);
        }
        const f32x4 uv = sU4[i * 16 + lm];
        const float wo = sWoh[i * 16 + lm];
        #pragma unroll
        for (int u = 0; u < 2; ++u) {
            #pragma unroll
            for (int t = ti; t < 4; ++t) {     // cols <= i carry zero weights
                acc[u][t][0] = fmaf(uv[t], h[u][0], acc[u][t][0]);
                acc[u][t][1] = fmaf(uv[t], h[u][1], acc[u][t][1]);
                acc[u][t][2] = fmaf(uv[t], h[u][2], acc[u][t][2]);
                acc[u][t][3] = fmaf(uv[t], h[u][3], acc[u][t][3]);
            }
            acc[u][4][0] = fmaf(wo, h[u][0], acc[u][4][0]);
            acc[u][4][1] = fmaf(wo, h[u][1], acc[u][4][1]);
            acc[u][4][2] = fmaf(wo, h[u][2], acc[u][4][2]);
            acc[u][4][3] = fmaf(wo, h[u][3], acc[u][4][3]);
        }
    }

    // ---- store head tile (cols 64..73) for both row-tiles ----
    if (lm < DIMO) {
        #pragma unroll
        for (int u = 0; u < 2; ++u) {
            const size_t orow0 = rowbase + u * 16 + lg * 4;
            #pragma unroll
            for (int r = 0; r < 4; ++r)
                out[(orow0 + r) * DIMO + lm] = acc[u][4][r];
        }
    }
}

extern "C" void kernel_launch(void* const* d_in, const int* in_sizes, int n_in,
                              void* d_out, int out_size, void* d_ws, size_t ws_size,
                              hipStream_t stream) {
    const float* x  = (const float*)d_in[0];
    const float* Wh = (const float*)d_in[1];
    const float* bh = (const float*)d_in[2];
    const float* Wo = (const float*)d_in[3];
    const float* bo = (const float*)d_in[4];
    float* out = (float*)d_out;

    const int B = in_sizes[0] / DIMD;      // 131072
    const int grid = B / TM;               // 512

    hipLaunchKernelGGL(caspernet_kernel, dim3(grid), dim3(BLOCK), 0, stream,
                       x, Wh, bh, Wo, bo, out, B);
}

// Round 8
// 248.141 us; speedup vs baseline: 1.2847x; 1.0641x over previous
//
#include <hip/hip_runtime.h>
#include <math.h>

// CasperNet R8: B=131072, D=256, H=64, O=10.
// R7 (264us) still spilled at VGPR=128: the fully-unrolled ks-loop let the
// scheduler hoist ALL 8 iterations' x loads (2 tiles x 8 x 2 float4 -> up
// to 256 regs in flight). Fix: #pragma unroll 1 on the ks loop -- only one
// body's 4 float4 loads (16 regs) live; TLP (16 waves/CU) hides latency.
// Live set ~80 < 128 cap -> no spill.
// Structure (verified R5-R7): MFMA phase-1, C-layout col=lane&15,
// row=(lane>>4)*4+reg; cascade directly on C-frags; 2 chains/wave;
// sigmoid via v_rcp_f32; __launch_bounds__(512,2) -> 128-VGPR cap.

#define DIMD 256
#define DIMH 64
#define DIMO 10
#define DT   320
#define NT   5        // 5 n-tiles of 16 = 80 cols (74 used)
#define TM   256      // rows per block: 8 waves x 32
#define BLOCK 512

typedef __attribute__((ext_vector_type(4))) float f32x4;
typedef __attribute__((ext_vector_type(8))) short bf16x8;

__device__ inline unsigned short f2bf(float f) {
    union { float f; unsigned u; } v; v.f = f;
    unsigned r = v.u + 0x7FFFu + ((v.u >> 16) & 1u);   // RNE
    return (unsigned short)(r >> 16);
}

__device__ inline float sigm(float s) {
    return __builtin_amdgcn_rcpf(1.0f + __expf(-s));   // v_rcp_f32: 1 instr
}

__global__ __launch_bounds__(BLOCK, 2) void caspernet_kernel(
    const float* __restrict__ x,    // [B, 256]
    const float* __restrict__ Wh,   // [64, 320]
    const float* __restrict__ bh,   // [64]
    const float* __restrict__ Wo,   // [10, 320]
    const float* __restrict__ bo,   // [10]
    float* __restrict__ out,        // [B, 10]
    int B)
{
    __shared__ short sW[80 * DIMD];     // bf16 [n][k], k XOR-swizzled; 40KB
    __shared__ f32x4 sU4[DIMH * 16];    // [i][c]: U for cols c+16t;     16KB
    __shared__ float sWoh[DIMH * 16];   // [i][c]: head col c (0 pad);    4KB
    __shared__ float sBias[80];

    const int tid = threadIdx.x;

    // ---- stage W1 = [Wh_x; Wo_x] as bf16, swizzled ----
    for (int idx = tid; idx < 80 * 64; idx += BLOCK) {   // 80 rows x 64 float4
        const int n = idx >> 6, k0 = (idx & 63) * 4;
        float4 v = make_float4(0.f, 0.f, 0.f, 0.f);
        if (n < DIMH)      v = *reinterpret_cast<const float4*>(Wh + n * DT + k0);
        else if (n < 74)   v = *reinterpret_cast<const float4*>(Wo + (n - 64) * DT + k0);
        const int kz = k0 ^ ((n & 7) << 3);
        short* d = sW + n * DIMD + kz;
        d[0] = (short)f2bf(v.x); d[1] = (short)f2bf(v.y);
        d[2] = (short)f2bf(v.z); d[3] = (short)f2bf(v.w);
    }
    // ---- cascade weights (pre-masked) + head + bias ----
    for (int idx = tid; idx < DIMH * 16; idx += BLOCK) {
        const int i = idx >> 4, c = idx & 15;
        f32x4 u;
        u[0] = (c      > i) ? Wh[(c     ) * DT + DIMD + i] : 0.f;
        u[1] = (16 + c > i) ? Wh[(16 + c) * DT + DIMD + i] : 0.f;
        u[2] = (32 + c > i) ? Wh[(32 + c) * DT + DIMD + i] : 0.f;
        u[3] = (48 + c > i) ? Wh[(48 + c) * DT + DIMD + i] : 0.f;
        sU4[idx] = u;
        sWoh[idx] = (c < DIMO) ? Wo[c * DT + DIMD + i] : 0.f;
    }
    if (tid < 80) sBias[tid] = (tid < 64) ? bh[tid] : ((tid < 74) ? bo[tid - 64] : 0.f);
    __syncthreads();

    const int l  = tid & 63;
    const int w  = tid >> 6;            // wave 0..7 -> rows w*32 .. w*32+31
    const int lm = l & 15, lg = l >> 4;
    const size_t rowbase = (size_t)blockIdx.x * TM + w * 32;

    // ---- phase 1: two 16-row tiles per wave; unroll capped to bound the
    //      load window (the R7 spill source) ----
    const float* xr0 = x + (rowbase +      lm) * DIMD + lg * 8;
    const float* xr1 = x + (rowbase + 16 + lm) * DIMD + lg * 8;

    f32x4 acc[2][NT];
    #pragma unroll
    for (int u = 0; u < 2; ++u)
        #pragma unroll
        for (int t = 0; t < NT; ++t) acc[u][t] = (f32x4){0.f, 0.f, 0.f, 0.f};

    #pragma unroll 1
    for (int ks = 0; ks < 8; ++ks) {
        const float4 xa0 = *reinterpret_cast<const float4*>(xr0 + ks * 32);
        const float4 xb0 = *reinterpret_cast<const float4*>(xr0 + ks * 32 + 4);
        const float4 xa1 = *reinterpret_cast<const float4*>(xr1 + ks * 32);
        const float4 xb1 = *reinterpret_cast<const float4*>(xr1 + ks * 32 + 4);
        bf16x8 af0, af1;
        af0[0] = (short)f2bf(xa0.x); af0[1] = (short)f2bf(xa0.y);
        af0[2] = (short)f2bf(xa0.z); af0[3] = (short)f2bf(xa0.w);
        af0[4] = (short)f2bf(xb0.x); af0[5] = (short)f2bf(xb0.y);
        af0[6] = (short)f2bf(xb0.z); af0[7] = (short)f2bf(xb0.w);
        af1[0] = (short)f2bf(xa1.x); af1[1] = (short)f2bf(xa1.y);
        af1[2] = (short)f2bf(xa1.z); af1[3] = (short)f2bf(xa1.w);
        af1[4] = (short)f2bf(xb1.x); af1[5] = (short)f2bf(xb1.y);
        af1[6] = (short)f2bf(xb1.z); af1[7] = (short)f2bf(xb1.w);
        #pragma unroll
        for (int t = 0; t < NT; ++t) {
            const int n = t * 16 + lm;
            const int kz = (lg * 8 + ks * 32) ^ ((n & 7) << 3);
            const bf16x8 bf = *reinterpret_cast<const bf16x8*>(sW + n * DIMD + kz);
            acc[0][t] = __builtin_amdgcn_mfma_f32_16x16x32_bf16(af0, bf, acc[0][t], 0, 0, 0);
            acc[1][t] = __builtin_amdgcn_mfma_f32_16x16x32_bf16(af1, bf, acc[1][t], 0, 0, 0);
        }
    }
    #pragma unroll
    for (int t = 0; t < NT; ++t) {
        const float bt = sBias[t * 16 + lm];
        #pragma unroll
        for (int u = 0; u < 2; ++u) {
            acc[u][t][0] += bt; acc[u][t][1] += bt;
            acc[u][t][2] += bt; acc[u][t][3] += bt;
        }
    }

    // ---- phase 2: two interleaved cascade chains ----
    const int gbase = l & 48;
    #pragma unroll
    for (int i = 0; i < DIMH; ++i) {
        const int ti = i >> 4, ci = i & 15;
        float h[2][4];
        #pragma unroll
        for (int u = 0; u < 2; ++u) {
            const float s0 = __shfl(acc[u][ti][0], gbase | ci, 64);
            const float s1 = __shfl(acc[u][ti][1], gbase | ci, 64);
            const float s2 = __shfl(acc[u][ti][2], gbase | ci, 64);
            const float s3 = __shfl(acc[u][ti][3], gbase | ci, 64);
            h[u][0] = sigm(s0); h[u][1] = sigm(s1);
            h[u][2] = sigm(s2); h[u][3] = sigm(s3);
        }
        const f32x4 uv = sU4[i * 16 + lm];
        const float wo = sWoh[i * 16 + lm];
        #pragma unroll
        for (int u = 0; u < 2; ++u) {
            #pragma unroll
            for (int t = ti; t < 4; ++t) {     // cols <= i carry zero weights
                acc[u][t][0] = fmaf(uv[t], h[u][0], acc[u][t][0]);
                acc[u][t][1] = fmaf(uv[t], h[u][1], acc[u][t][1]);
                acc[u][t][2] = fmaf(uv[t], h[u][2], acc[u][t][2]);
                acc[u][t][3] = fmaf(uv[t], h[u][3], acc[u][t][3]);
            }
            acc[u][4][0] = fmaf(wo, h[u][0], acc[u][4][0]);
            acc[u][4][1] = fmaf(wo, h[u][1], acc[u][4][1]);
            acc[u][4][2] = fmaf(wo, h[u][2], acc[u][4][2]);
            acc[u][4][3] = fmaf(wo, h[u][3], acc[u][4][3]);
        }
    }

    // ---- store head tile (cols 64..73) for both row-tiles ----
    if (lm < DIMO) {
        #pragma unroll
        for (int u = 0; u < 2; ++u) {
            const size_t orow0 = rowbase + u * 16 + lg * 4;
            #pragma unroll
            for (int r = 0; r < 4; ++r)
                out[(orow0 + r) * DIMO + lm] = acc[u][4][r];
        }
    }
}

extern "C" void kernel_launch(void* const* d_in, const int* in_sizes, int n_in,
                              void* d_out, int out_size, void* d_ws, size_t ws_size,
                              hipStream_t stream) {
    const float* x  = (const float*)d_in[0];
    const float* Wh = (const float*)d_in[1];
    const float* bh = (const float*)d_in[2];
    const float* Wo = (const float*)d_in[3];
    const float* bo = (const float*)d_in[4];
    float* out = (float*)d_out;

    const int B = in_sizes[0] / DIMD;      // 131072
    const int grid = B / TM;               // 512

    hipLaunchKernelGGL(caspernet_kernel, dim3(grid), dim3(BLOCK), 0, stream,
                       x, Wh, bh, Wo, bo, out, B);
}

// Round 9
// 63.547 us; speedup vs baseline: 5.0168x; 3.9049x over previous
//
#include <hip/hip_runtime.h>
#include <math.h>

// CasperNet R9: B=131072, D=256, H=64, O=10.
// Spill post-mortem (R5-R8): 1 chain/wave = 88 VGPR, clean (R5, WRITE=5.1MB
// ideal); every 2-chain/wave variant needs ~128+ and spills at the cap
// (R6-R8, WRITE 240-440MB). Fix: take R5's per-wave structure verbatim and
// scale occupancy by waves-per-block instead of chains-per-wave:
//   BLOCK=512, TM=128 -> 8 waves x one 16-row tile each; LDS ~60.5KB ->
//   2 blocks/CU -> 16 waves/CU (50% occ, was 25% in R5).
// __launch_bounds__(512,2) -> 128-VGPR cap, ~40 regs headroom.
// Layout (verified R5): MFMA C: col=lane&15, row=(lane>>4)*4+reg; cascade
// runs directly on C-frags; sigmoid via v_rcp_f32.

#define DIMD 256
#define DIMH 64
#define DIMO 10
#define DT   320
#define NT   5        // 5 n-tiles of 16 = 80 cols (74 used)
#define TM   128      // rows per block: 8 waves x 16
#define BLOCK 512

typedef __attribute__((ext_vector_type(4))) float f32x4;
typedef __attribute__((ext_vector_type(8))) short bf16x8;

__device__ inline unsigned short f2bf(float f) {
    union { float f; unsigned u; } v; v.f = f;
    unsigned r = v.u + 0x7FFFu + ((v.u >> 16) & 1u);   // RNE
    return (unsigned short)(r >> 16);
}

__device__ inline float sigm(float s) {
    return __builtin_amdgcn_rcpf(1.0f + __expf(-s));   // v_rcp_f32: 1 instr
}

__global__ __launch_bounds__(BLOCK, 2) void caspernet_kernel(
    const float* __restrict__ x,    // [B, 256]
    const float* __restrict__ Wh,   // [64, 320]
    const float* __restrict__ bh,   // [64]
    const float* __restrict__ Wo,   // [10, 320]
    const float* __restrict__ bo,   // [10]
    float* __restrict__ out,        // [B, 10]
    int B)
{
    __shared__ short sW[80 * DIMD];     // bf16 [n][k], k XOR-swizzled; 40KB
    __shared__ f32x4 sU4[DIMH * 16];    // [i][c]: U for cols c+16t;     16KB
    __shared__ float sWoh[DIMH * 16];   // [i][c]: head col c (0 pad);    4KB
    __shared__ float sBias[80];

    const int tid = threadIdx.x;

    // ---- stage W1 = [Wh_x; Wo_x] as bf16, swizzled ----
    for (int idx = tid; idx < 80 * 64; idx += BLOCK) {   // 80 rows x 64 float4
        const int n = idx >> 6, k0 = (idx & 63) * 4;
        float4 v = make_float4(0.f, 0.f, 0.f, 0.f);
        if (n < DIMH)      v = *reinterpret_cast<const float4*>(Wh + n * DT + k0);
        else if (n < 74)   v = *reinterpret_cast<const float4*>(Wo + (n - 64) * DT + k0);
        const int kz = k0 ^ ((n & 7) << 3);
        short* d = sW + n * DIMD + kz;
        d[0] = (short)f2bf(v.x); d[1] = (short)f2bf(v.y);
        d[2] = (short)f2bf(v.z); d[3] = (short)f2bf(v.w);
    }
    // ---- cascade weights (pre-masked) + head + bias ----
    for (int idx = tid; idx < DIMH * 16; idx += BLOCK) {
        const int i = idx >> 4, c = idx & 15;
        f32x4 u;
        u[0] = (c      > i) ? Wh[(c     ) * DT + DIMD + i] : 0.f;
        u[1] = (16 + c > i) ? Wh[(16 + c) * DT + DIMD + i] : 0.f;
        u[2] = (32 + c > i) ? Wh[(32 + c) * DT + DIMD + i] : 0.f;
        u[3] = (48 + c > i) ? Wh[(48 + c) * DT + DIMD + i] : 0.f;
        sU4[idx] = u;
        sWoh[idx] = (c < DIMO) ? Wo[c * DT + DIMD + i] : 0.f;
    }
    if (tid < 80) sBias[tid] = (tid < 64) ? bh[tid] : ((tid < 74) ? bo[tid - 64] : 0.f);
    __syncthreads();

    const int l  = tid & 63;
    const int w  = tid >> 6;            // wave 0..7 -> rows w*16..w*16+15
    const int lm = l & 15, lg = l >> 4;

    // ---- phase 1: one 16-row tile per wave ----
    const size_t rowA = (size_t)blockIdx.x * TM + w * 16 + lm;
    const float* xr = x + rowA * DIMD + lg * 8;

    f32x4 acc[NT];
    #pragma unroll
    for (int t = 0; t < NT; ++t) acc[t] = (f32x4){0.f, 0.f, 0.f, 0.f};

    #pragma unroll
    for (int ks = 0; ks < 8; ++ks) {
        const float4 xa = *reinterpret_cast<const float4*>(xr + ks * 32);
        const float4 xb = *reinterpret_cast<const float4*>(xr + ks * 32 + 4);
        bf16x8 af;
        af[0] = (short)f2bf(xa.x); af[1] = (short)f2bf(xa.y);
        af[2] = (short)f2bf(xa.z); af[3] = (short)f2bf(xa.w);
        af[4] = (short)f2bf(xb.x); af[5] = (short)f2bf(xb.y);
        af[6] = (short)f2bf(xb.z); af[7] = (short)f2bf(xb.w);
        #pragma unroll
        for (int t = 0; t < NT; ++t) {
            const int n = t * 16 + lm;
            const int kz = (lg * 8 + ks * 32) ^ ((n & 7) << 3);
            const bf16x8 bf = *reinterpret_cast<const bf16x8*>(sW + n * DIMD + kz);
            acc[t] = __builtin_amdgcn_mfma_f32_16x16x32_bf16(af, bf, acc[t], 0, 0, 0);
        }
    }
    #pragma unroll
    for (int t = 0; t < NT; ++t) {
        const float bt = sBias[t * 16 + lm];
        acc[t][0] += bt; acc[t][1] += bt; acc[t][2] += bt; acc[t][3] += bt;
    }

    // ---- phase 2: cascade on the C-layout ----
    const int gbase = l & 48;
    #pragma unroll
    for (int i = 0; i < DIMH; ++i) {
        const int ti = i >> 4, ci = i & 15;
        const float s0 = __shfl(acc[ti][0], gbase | ci, 64);
        const float s1 = __shfl(acc[ti][1], gbase | ci, 64);
        const float s2 = __shfl(acc[ti][2], gbase | ci, 64);
        const float s3 = __shfl(acc[ti][3], gbase | ci, 64);
        const float h0 = sigm(s0), h1 = sigm(s1);
        const float h2 = sigm(s2), h3 = sigm(s3);
        const f32x4 uv = sU4[i * 16 + lm];
        const float wo = sWoh[i * 16 + lm];
        #pragma unroll
        for (int t = ti; t < 4; ++t) {          // cols <= i carry zero weights
            acc[t][0] = fmaf(uv[t], h0, acc[t][0]);
            acc[t][1] = fmaf(uv[t], h1, acc[t][1]);
            acc[t][2] = fmaf(uv[t], h2, acc[t][2]);
            acc[t][3] = fmaf(uv[t], h3, acc[t][3]);
        }
        acc[4][0] = fmaf(wo, h0, acc[4][0]);
        acc[4][1] = fmaf(wo, h1, acc[4][1]);
        acc[4][2] = fmaf(wo, h2, acc[4][2]);
        acc[4][3] = fmaf(wo, h3, acc[4][3]);
    }

    // ---- store head tile (cols 64..73 = C-tile 4) ----
    if (lm < DIMO) {
        const size_t orow0 = (size_t)blockIdx.x * TM + w * 16 + lg * 4;
        #pragma unroll
        for (int r = 0; r < 4; ++r)
            out[(orow0 + r) * DIMO + lm] = acc[4][r];
    }
}

extern "C" void kernel_launch(void* const* d_in, const int* in_sizes, int n_in,
                              void* d_out, int out_size, void* d_ws, size_t ws_size,
                              hipStream_t stream) {
    const float* x  = (const float*)d_in[0];
    const float* Wh = (const float*)d_in[1];
    const float* bh = (const float*)d_in[2];
    const float* Wo = (const float*)d_in[3];
    const float* bo = (const float*)d_in[4];
    float* out = (float*)d_out;

    const int B = in_sizes[0] / DIMD;      // 131072
    const int grid = B / TM;               // 1024

    hipLaunchKernelGGL(caspernet_kernel, dim3(grid), dim3(BLOCK), 0, stream,
                       x, Wh, bh, Wo, bo, out, B);
}